// Round 1
// baseline (299.632 us; speedup 1.0000x reference)
//
#include <hip/hip_runtime.h>
#include <cstdint>
#include <cstddef>

typedef unsigned short u16;
typedef __bf16 bf16;
typedef bf16 __attribute__((ext_vector_type(8))) bf16x8;
typedef float __attribute__((ext_vector_type(4))) f32x4;
typedef u16 __attribute__((ext_vector_type(8))) u16x8;

// SCALE * log2(e) folded into Q so softmax runs in exp2 domain
#define QSCALE 0.18033688011112042f

__device__ __forceinline__ u16 f2b(float x) {
  unsigned u = __float_as_uint(x);
  unsigned r = (u + 0x7fffu + ((u >> 16) & 1u)) >> 16;   // RNE
  return (u16)r;
}

__device__ __forceinline__ void gl_lds16(const void* g, void* lds) {
  __builtin_amdgcn_global_load_lds(
      (const __attribute__((address_space(1))) unsigned int*)g,
      (__attribute__((address_space(3))) unsigned int*)lds, 16, 0, 0);
}

// ---------------- cast fp32 -> bf16 (vectorized) ----------------
__global__ __launch_bounds__(256) void castk(const float* __restrict__ in,
                                             u16* __restrict__ out, int n) {
  int i = (blockIdx.x * 256 + threadIdx.x) * 8;
  if (i >= n) return;
  float4 a = *(const float4*)(in + i);
  float4 b = *(const float4*)(in + i + 4);
  u16x8 v;
  v[0] = f2b(a.x); v[1] = f2b(a.y); v[2] = f2b(a.z); v[3] = f2b(a.w);
  v[4] = f2b(b.x); v[5] = f2b(b.y); v[6] = f2b(b.z); v[7] = f2b(b.w);
  *(u16x8*)(out + i) = v;
}

// ---------------- GEMM: C = A(MxK) * B(NxK)^T, bf16, m97-style ----------------
// EPI=0: scatter epilogue -> Q (scaled), K, V^T buffers for attention
// EPI=1: fp32 out = (acc + bias[c]) * msk[r]
template <int EPI>
__global__ __launch_bounds__(256) void gemm_bt(
    const u16* __restrict__ A, const u16* __restrict__ B, int K, int N, int nbm,
    u16* __restrict__ Qo, u16* __restrict__ Ko, u16* __restrict__ Vo,
    float* __restrict__ Co, const float* __restrict__ bias,
    const float* __restrict__ msk) {
  __shared__ u16 As[128 * 32];
  __shared__ u16 Bs[128 * 32];
  const int tid = threadIdx.x;
  const int lane = tid & 63, wave = tid >> 6;
  const int fr = lane & 15, fg = lane >> 4;
  const int wr = wave >> 1, wc = wave & 1;
  const int bid = blockIdx.x;
  const int bm = bid % nbm, bn = bid / nbm;

  const u16* Ab = A + (size_t)bm * 128 * K;
  const u16* Bb = B + (size_t)bn * 128 * K;

  f32x4 acc[4][4] = {};

  const int c0 = wave * 64 + lane;
  const int row0 = c0 >> 2, cb0 = c0 & 3;
  const int c1 = 256 + c0;
  const int row1 = c1 >> 2, cb1 = c1 & 3;

  for (int k0 = 0; k0 < K; k0 += 32) {
    __syncthreads();
    gl_lds16(Ab + (size_t)row0 * K + k0 + cb0 * 8, (char*)As + wave * 1024);
    gl_lds16(Bb + (size_t)row0 * K + k0 + cb0 * 8, (char*)Bs + wave * 1024);
    gl_lds16(Ab + (size_t)row1 * K + k0 + cb1 * 8, (char*)As + 4096 + wave * 1024);
    gl_lds16(Bb + (size_t)row1 * K + k0 + cb1 * 8, (char*)Bs + 4096 + wave * 1024);
    __syncthreads();
    bf16x8 af[4], bfv[4];
#pragma unroll
    for (int mi = 0; mi < 4; ++mi)
      af[mi] = *(const bf16x8*)(As + (wr * 64 + mi * 16 + fr) * 32 + fg * 8);
#pragma unroll
    for (int ni = 0; ni < 4; ++ni)
      bfv[ni] = *(const bf16x8*)(Bs + (wc * 64 + ni * 16 + fr) * 32 + fg * 8);
#pragma unroll
    for (int mi = 0; mi < 4; ++mi)
#pragma unroll
      for (int ni = 0; ni < 4; ++ni)
        acc[mi][ni] = __builtin_amdgcn_mfma_f32_16x16x32_bf16(af[mi], bfv[ni],
                                                              acc[mi][ni], 0, 0, 0);
  }

  const int gr0 = bm * 128 + wr * 64;
  const int gc0 = bn * 128 + wc * 64;
  if constexpr (EPI == 0) {
#pragma unroll
    for (int mi = 0; mi < 4; ++mi) {
      const int rb = gr0 + mi * 16 + fg * 4;
      const int b = rb >> 10, t = rb & 1023;
#pragma unroll
      for (int ni = 0; ni < 4; ++ni) {
        const int c = gc0 + ni * 16 + fr;
        const int region = c >> 10, cc = c & 1023;
        const int h = cc >> 6, d = cc & 63;
        const size_t bh = (size_t)(b * 16 + h);
        if (region == 0) {
#pragma unroll
          for (int g = 0; g < 4; ++g)
            Qo[(bh * 1024 + t + g) * 64 + d] = f2b(acc[mi][ni][g] * QSCALE);
        } else if (region == 1) {
#pragma unroll
          for (int g = 0; g < 4; ++g)
            Ko[(bh * 1024 + t + g) * 64 + d] = f2b(acc[mi][ni][g]);
        } else {
          ushort4 pv;
          pv.x = f2b(acc[mi][ni][0]);
          pv.y = f2b(acc[mi][ni][1]);
          pv.z = f2b(acc[mi][ni][2]);
          pv.w = f2b(acc[mi][ni][3]);
          *(ushort4*)(Vo + (bh * 64 + d) * 1024 + t) = pv;  // V transposed: [bh][d][t]
        }
      }
    }
  } else {
#pragma unroll
    for (int mi = 0; mi < 4; ++mi) {
      const int rb = gr0 + mi * 16 + fg * 4;
#pragma unroll
      for (int ni = 0; ni < 4; ++ni) {
        const int c = gc0 + ni * 16 + fr;
        const float bo = bias[c];
#pragma unroll
        for (int g = 0; g < 4; ++g) {
          const int r = rb + g;
          Co[(size_t)r * N + c] = (acc[mi][ni][g] + bo) * msk[r];
        }
      }
    }
  }
}

// ---------------- causal flash attention, bf16 MFMA ----------------
// grid: 1024 blocks = 128 (b,h) x 8 q-tiles of 128 rows; 4 waves x 32 q-rows
__global__ __launch_bounds__(256) void attnk(const u16* __restrict__ Qb,
                                             const u16* __restrict__ Kb,
                                             const u16* __restrict__ Vtb,
                                             const float* __restrict__ msk,
                                             u16* __restrict__ Ob) {
  __shared__ u16 Ks[64 * 64];        // [t][d], 128B rows, XOR-swizzled
  __shared__ u16 Vs[64 * 64];        // [d][t], 128B rows, XOR-swizzled
  __shared__ u16 Ps[4][32 * 72];     // per-wave P tile, stride 72 (16B-aligned rows)
  const int tid = threadIdx.x;
  const int lane = tid & 63, wave = tid >> 6;
  const int fr = lane & 15, fg = lane >> 4;
  const int bid = blockIdx.x;
  const int qi = 7 - (bid & 7);      // heavy tiles first
  const int bh = bid >> 3;
  const int b = bh >> 4, h = bh & 15;
  const int qw = qi * 128 + wave * 32;

  bf16x8 qf[2][2];
#pragma unroll
  for (int mt = 0; mt < 2; ++mt)
#pragma unroll
    for (int kc = 0; kc < 2; ++kc)
      qf[mt][kc] = *(const bf16x8*)(Qb + ((size_t)bh * 1024 + qw + mt * 16 + fr) * 64 +
                                    kc * 32 + fg * 8);

  f32x4 o[2][4] = {};
  float mrun[8], lrun[8];
#pragma unroll
  for (int i = 0; i < 8; ++i) { mrun[i] = -3.0e38f; lrun[i] = 0.f; }

  const int cc0 = wave * 64 + lane;
  const int krow0 = cc0 >> 3, kcb0 = (cc0 & 7) ^ (krow0 & 7);
  const int cc1 = 256 + cc0;
  const int krow1 = cc1 >> 3, kcb1 = (cc1 & 7) ^ (krow1 & 7);

  const int nkb = qi * 2 + 2;
  for (int kb = 0; kb < nkb; ++kb) {
    __syncthreads();
    gl_lds16(Kb + ((size_t)bh * 1024 + kb * 64 + krow0) * 64 + kcb0 * 8,
             (char*)Ks + wave * 1024);
    gl_lds16(Vtb + ((size_t)bh * 64 + krow0) * 1024 + kb * 64 + kcb0 * 8,
             (char*)Vs + wave * 1024);
    gl_lds16(Kb + ((size_t)bh * 1024 + kb * 64 + krow1) * 64 + kcb1 * 8,
             (char*)Ks + 4096 + wave * 1024);
    gl_lds16(Vtb + ((size_t)bh * 64 + krow1) * 1024 + kb * 64 + kcb1 * 8,
             (char*)Vs + 4096 + wave * 1024);
    __syncthreads();
    if (kb * 64 > qw + 31) continue;  // fully masked for this wave (barrier counts match)

    // --- QK^T ---
    bf16x8 kf[4][2];
#pragma unroll
    for (int nt = 0; nt < 4; ++nt) {
      const int krow = nt * 16 + fr;
#pragma unroll
      for (int kc = 0; kc < 2; ++kc) {
        const int cb = (kc * 4 + fg) ^ (krow & 7);
        kf[nt][kc] = *(const bf16x8*)(Ks + krow * 64 + cb * 8);
      }
    }
    f32x4 s[2][4];
    const f32x4 z = {0.f, 0.f, 0.f, 0.f};
#pragma unroll
    for (int mt = 0; mt < 2; ++mt)
#pragma unroll
      for (int nt = 0; nt < 4; ++nt) {
        s[mt][nt] = __builtin_amdgcn_mfma_f32_16x16x32_bf16(qf[mt][0], kf[nt][0], z, 0, 0, 0);
        s[mt][nt] = __builtin_amdgcn_mfma_f32_16x16x32_bf16(qf[mt][1], kf[nt][1], s[mt][nt], 0, 0, 0);
      }

    // --- mask (causal + key padding) ---
    const bool edge = (kb * 64 + 63 > qw);
    float kmv[4];
#pragma unroll
    for (int nt = 0; nt < 4; ++nt) kmv[nt] = msk[b * 1024 + kb * 64 + nt * 16 + fr];
#pragma unroll
    for (int mt = 0; mt < 2; ++mt)
#pragma unroll
      for (int nt = 0; nt < 4; ++nt) {
        const int j = kb * 64 + nt * 16 + fr;
#pragma unroll
        for (int g = 0; g < 4; ++g) {
          const int q = qw + mt * 16 + fg * 4 + g;
          if ((edge && j > q) || kmv[nt] == 0.f) s[mt][nt][g] = -3.0e38f;
        }
      }

    // --- online softmax (exp2 domain; QSCALE folded into Q) ---
#pragma unroll
    for (int mt = 0; mt < 2; ++mt)
#pragma unroll
      for (int g = 0; g < 4; ++g) {
        const int ri = mt * 4 + g;
        float mx = fmaxf(fmaxf(s[mt][0][g], s[mt][1][g]), fmaxf(s[mt][2][g], s[mt][3][g]));
        mx = fmaxf(mx, __shfl_xor(mx, 1));
        mx = fmaxf(mx, __shfl_xor(mx, 2));
        mx = fmaxf(mx, __shfl_xor(mx, 4));
        mx = fmaxf(mx, __shfl_xor(mx, 8));
        const float nm = fmaxf(mrun[ri], mx);
        const float sc = exp2f(mrun[ri] - nm);
        mrun[ri] = nm;
        float rs = 0.f;
#pragma unroll
        for (int nt = 0; nt < 4; ++nt) {
          const float p = exp2f(s[mt][nt][g] - nm);
          s[mt][nt][g] = p;
          rs += p;
        }
        rs += __shfl_xor(rs, 1);
        rs += __shfl_xor(rs, 2);
        rs += __shfl_xor(rs, 4);
        rs += __shfl_xor(rs, 8);
        lrun[ri] = lrun[ri] * sc + rs;
#pragma unroll
        for (int dt = 0; dt < 4; ++dt) o[mt][dt][g] *= sc;
      }

    // --- P -> LDS (per-wave region; compiler orders via lgkmcnt) ---
#pragma unroll
    for (int mt = 0; mt < 2; ++mt)
#pragma unroll
      for (int nt = 0; nt < 4; ++nt)
#pragma unroll
        for (int g = 0; g < 4; ++g)
          Ps[wave][(mt * 16 + fg * 4 + g) * 72 + nt * 16 + fr] = f2b(s[mt][nt][g]);

    // --- PV ---
#pragma unroll
    for (int jc = 0; jc < 2; ++jc) {
      bf16x8 pa[2];
#pragma unroll
      for (int mt = 0; mt < 2; ++mt)
        pa[mt] = *(const bf16x8*)(&Ps[wave][(mt * 16 + fr) * 72 + jc * 32 + fg * 8]);
#pragma unroll
      for (int dt = 0; dt < 4; ++dt) {
        const int vrow = dt * 16 + fr;
        const int cb = (jc * 4 + fg) ^ (vrow & 7);
        const bf16x8 vf = *(const bf16x8*)(Vs + vrow * 64 + cb * 8);
#pragma unroll
        for (int mt = 0; mt < 2; ++mt)
          o[mt][dt] = __builtin_amdgcn_mfma_f32_16x16x32_bf16(pa[mt], vf, o[mt][dt], 0, 0, 0);
      }
    }
  }

  // --- epilogue: O / l -> Ob[b][t][h*64+d] (bf16) ---
#pragma unroll
  for (int mt = 0; mt < 2; ++mt)
#pragma unroll
    for (int g = 0; g < 4; ++g) {
      const int ri = mt * 4 + g;
      const float inv = 1.0f / lrun[ri];
      const int q = qw + mt * 16 + fg * 4 + g;
#pragma unroll
      for (int dt = 0; dt < 4; ++dt)
        Ob[((size_t)b * 1024 + q) * 1024 + h * 64 + dt * 16 + fr] =
            f2b(o[mt][dt][g] * inv);
    }
}

// ---------------- launcher ----------------
extern "C" void kernel_launch(void* const* d_in, const int* in_sizes, int n_in,
                              void* d_out, int out_size, void* d_ws, size_t ws_size,
                              hipStream_t stream) {
  (void)in_sizes; (void)n_in; (void)out_size; (void)ws_size;
  const float* x = (const float*)d_in[0];
  const float* m = (const float*)d_in[1];
  const float* w_qkv = (const float*)d_in[2];
  const float* w_out = (const float*)d_in[3];
  const float* b_out = (const float*)d_in[4];
  float* out = (float*)d_out;

  char* ws = (char*)d_ws;
  const size_t MB = 1u << 20;
  u16* Xb    = (u16*)(ws + 0);         // 16MB, reused as Ob after GEMM1
  u16* Wqkvb = (u16*)(ws + 16 * MB);   // 6MB
  u16* Woutb = (u16*)(ws + 22 * MB);   // 2MB
  u16* Qb    = (u16*)(ws + 24 * MB);   // 16MB
  u16* Kb    = (u16*)(ws + 40 * MB);   // 16MB
  u16* Vtb   = (u16*)(ws + 56 * MB);   // 16MB  -> total 72MB
  u16* Ob    = Xb;                      // alias: X dead after GEMM1

  // casts
  castk<<<4096, 256, 0, stream>>>(x, Xb, 8 * 1024 * 1024);
  castk<<<1536, 256, 0, stream>>>(w_qkv, Wqkvb, 3072 * 1024);
  castk<<<512, 256, 0, stream>>>(w_out, Woutb, 1024 * 1024);

  // GEMM1: qkv = X @ Wqkv^T, scatter to Q(scaled)/K/V^T
  gemm_bt<0><<<64 * 24, 256, 0, stream>>>(Xb, Wqkvb, 1024, 3072, 64,
                                          Qb, Kb, Vtb, nullptr, nullptr, nullptr);

  // flash attention
  attnk<<<1024, 256, 0, stream>>>(Qb, Kb, Vtb, m, Ob);

  // GEMM2: out = (O @ Wout^T + b_out) * m
  gemm_bt<1><<<64 * 8, 256, 0, stream>>>(Ob, Woutb, 1024, 1024, 64,
                                         nullptr, nullptr, nullptr, out, b_out, m);
}

// Round 2
// 190.070 us; speedup vs baseline: 1.5764x; 1.5764x over previous
//
#include <hip/hip_runtime.h>
#include <cstdint>
#include <cstddef>

typedef unsigned short u16;
typedef __bf16 bf16;
typedef bf16 __attribute__((ext_vector_type(4))) bf16x4;
typedef bf16 __attribute__((ext_vector_type(8))) bf16x8;
typedef float __attribute__((ext_vector_type(4))) f32x4;
typedef u16 __attribute__((ext_vector_type(8))) u16x8;

// SCALE * log2(e) folded into Q so softmax runs in exp2 domain
#define QSCALE 0.18033688011112042f

__device__ __forceinline__ u16 f2b(float x) {
  unsigned u = __float_as_uint(x);
  unsigned r = (u + 0x7fffu + ((u >> 16) & 1u)) >> 16;   // RNE
  return (u16)r;
}

__device__ __forceinline__ void gl_lds16(const void* g, void* lds) {
  __builtin_amdgcn_global_load_lds(
      (const __attribute__((address_space(1))) unsigned int*)g,
      (__attribute__((address_space(3))) unsigned int*)lds, 16, 0, 0);
}

// ---------------- cast fp32 -> bf16 (vectorized) ----------------
__global__ __launch_bounds__(256) void castk(const float* __restrict__ in,
                                             u16* __restrict__ out, int n) {
  int i = (blockIdx.x * 256 + threadIdx.x) * 8;
  if (i >= n) return;
  float4 a = *(const float4*)(in + i);
  float4 b = *(const float4*)(in + i + 4);
  u16x8 v;
  v[0] = f2b(a.x); v[1] = f2b(a.y); v[2] = f2b(a.z); v[3] = f2b(a.w);
  v[4] = f2b(b.x); v[5] = f2b(b.y); v[6] = f2b(b.z); v[7] = f2b(b.w);
  *(u16x8*)(out + i) = v;
}

// ---------------- GEMM: C = A(MxK) * B(NxK)^T, bf16, m97-style ----------------
template <int EPI>
__global__ __launch_bounds__(256) void gemm_bt(
    const u16* __restrict__ A, const u16* __restrict__ B, int K, int N, int nbm,
    u16* __restrict__ Qo, u16* __restrict__ Ko, u16* __restrict__ Vo,
    float* __restrict__ Co, const float* __restrict__ bias,
    const float* __restrict__ msk) {
  __shared__ u16 As[128 * 32];
  __shared__ u16 Bs[128 * 32];
  const int tid = threadIdx.x;
  const int lane = tid & 63, wave = tid >> 6;
  const int fr = lane & 15, fg = lane >> 4;
  const int wr = wave >> 1, wc = wave & 1;
  const int bid = blockIdx.x;
  const int bm = bid % nbm, bn = bid / nbm;

  const u16* Ab = A + (size_t)bm * 128 * K;
  const u16* Bb = B + (size_t)bn * 128 * K;

  f32x4 acc[4][4] = {};

  const int c0 = wave * 64 + lane;
  const int row0 = c0 >> 2, cb0 = c0 & 3;
  const int c1 = 256 + c0;
  const int row1 = c1 >> 2, cb1 = c1 & 3;

  for (int k0 = 0; k0 < K; k0 += 32) {
    __syncthreads();
    gl_lds16(Ab + (size_t)row0 * K + k0 + cb0 * 8, (char*)As + wave * 1024);
    gl_lds16(Bb + (size_t)row0 * K + k0 + cb0 * 8, (char*)Bs + wave * 1024);
    gl_lds16(Ab + (size_t)row1 * K + k0 + cb1 * 8, (char*)As + 4096 + wave * 1024);
    gl_lds16(Bb + (size_t)row1 * K + k0 + cb1 * 8, (char*)Bs + 4096 + wave * 1024);
    __syncthreads();
    bf16x8 af[4], bfv[4];
#pragma unroll
    for (int mi = 0; mi < 4; ++mi)
      af[mi] = *(const bf16x8*)(As + (wr * 64 + mi * 16 + fr) * 32 + fg * 8);
#pragma unroll
    for (int ni = 0; ni < 4; ++ni)
      bfv[ni] = *(const bf16x8*)(Bs + (wc * 64 + ni * 16 + fr) * 32 + fg * 8);
#pragma unroll
    for (int mi = 0; mi < 4; ++mi)
#pragma unroll
      for (int ni = 0; ni < 4; ++ni)
        acc[mi][ni] = __builtin_amdgcn_mfma_f32_16x16x32_bf16(af[mi], bfv[ni],
                                                              acc[mi][ni], 0, 0, 0);
  }

  const int gr0 = bm * 128 + wr * 64;
  const int gc0 = bn * 128 + wc * 64;
  if constexpr (EPI == 0) {
#pragma unroll
    for (int mi = 0; mi < 4; ++mi) {
      const int rb = gr0 + mi * 16 + fg * 4;
      const int b = rb >> 10, t = rb & 1023;
#pragma unroll
      for (int ni = 0; ni < 4; ++ni) {
        const int c = gc0 + ni * 16 + fr;
        const int region = c >> 10, cc = c & 1023;
        const int h = cc >> 6, d = cc & 63;
        const size_t bh = (size_t)(b * 16 + h);
        if (region == 0) {
#pragma unroll
          for (int g = 0; g < 4; ++g)
            Qo[(bh * 1024 + t + g) * 64 + d] = f2b(acc[mi][ni][g] * QSCALE);
        } else if (region == 1) {
#pragma unroll
          for (int g = 0; g < 4; ++g)
            Ko[(bh * 1024 + t + g) * 64 + d] = f2b(acc[mi][ni][g]);
        } else {
          ushort4 pv;
          pv.x = f2b(acc[mi][ni][0]);
          pv.y = f2b(acc[mi][ni][1]);
          pv.z = f2b(acc[mi][ni][2]);
          pv.w = f2b(acc[mi][ni][3]);
          *(ushort4*)(Vo + (bh * 64 + d) * 1024 + t) = pv;  // V transposed: [bh][d][t]
        }
      }
    }
  } else {
#pragma unroll
    for (int mi = 0; mi < 4; ++mi) {
      const int rb = gr0 + mi * 16 + fg * 4;
#pragma unroll
      for (int ni = 0; ni < 4; ++ni) {
        const int c = gc0 + ni * 16 + fr;
        const float bo = bias[c];
#pragma unroll
        for (int g = 0; g < 4; ++g) {
          const int r = rb + g;
          Co[(size_t)r * N + c] = (acc[mi][ni][g] + bo) * msk[r];
        }
      }
    }
  }
}

// ---------------- causal flash attention, bf16 MFMA, swapped-QK^T softmax ---
// grid: 1024 blocks; qi via balanced table so every mod-256 coset of blocks
// carries equal total K-tile work (36 iters/CU); heavy tiles launch first.
__global__ __launch_bounds__(256) void attnk(const u16* __restrict__ Qb,
                                             const u16* __restrict__ Kb,
                                             const u16* __restrict__ Vtb,
                                             const float* __restrict__ msk,
                                             u16* __restrict__ Ob) {
  __shared__ u16 Ks[64 * 64];        // [t][d], XOR-swizzled via staged source
  __shared__ u16 Vs[64 * 64];        // [d][t], XOR-swizzled via staged source
  __shared__ u16 Ps[4][32 * 72];     // per-wave P tile [q][k], stride 72
  const int tid = threadIdx.x;
  const int lane = tid & 63, wave = tid >> 6;
  const int fr = lane & 15, fg = lane >> 4;
  const int bid = blockIdx.x;
  __constant__ static const int tab[8] = {7, 6, 0, 1, 5, 4, 2, 3};
  const int qi = tab[bid >> 7];
  const int bh = bid & 127;
  const int b = bh >> 4, h = bh & 15;
  const int qw = qi * 128 + wave * 32;

  bf16x8 qf[2][2];
#pragma unroll
  for (int ct = 0; ct < 2; ++ct)
#pragma unroll
    for (int kc = 0; kc < 2; ++kc)
      qf[ct][kc] = *(const bf16x8*)(Qb + ((size_t)bh * 1024 + qw + ct * 16 + fr) * 64 +
                                    kc * 32 + fg * 8);

  f32x4 o[2][4] = {};
  float mrun[2], lrun[2];
  mrun[0] = mrun[1] = -3.0e38f;
  lrun[0] = lrun[1] = 0.f;

  const int cc0 = wave * 64 + lane;
  const int krow0 = cc0 >> 3, kcb0 = (cc0 & 7) ^ (krow0 & 7);
  const int cc1 = 256 + cc0;
  const int krow1 = cc1 >> 3, kcb1 = (cc1 & 7) ^ (krow1 & 7);

  const int nkb = qi * 2 + 2;
  for (int kb = 0; kb < nkb; ++kb) {
    __syncthreads();
    gl_lds16(Kb + ((size_t)bh * 1024 + kb * 64 + krow0) * 64 + kcb0 * 8,
             (char*)Ks + wave * 1024);
    gl_lds16(Vtb + ((size_t)bh * 64 + krow0) * 1024 + kb * 64 + kcb0 * 8,
             (char*)Vs + wave * 1024);
    gl_lds16(Kb + ((size_t)bh * 1024 + kb * 64 + krow1) * 64 + kcb1 * 8,
             (char*)Ks + 4096 + wave * 1024);
    gl_lds16(Vtb + ((size_t)bh * 64 + krow1) * 1024 + kb * 64 + kcb1 * 8,
             (char*)Vs + 4096 + wave * 1024);
    __syncthreads();
    if (kb * 64 > qw + 31) continue;  // fully masked for this wave (barrier counts match)

    // --- S^T = K * Q^T : lane owns q-col = ct*16+fr, rows k = nt*16+fg*4+g ---
    f32x4 st[2][4];                  // [ct][nt]
    const f32x4 z = {0.f, 0.f, 0.f, 0.f};
#pragma unroll
    for (int nt = 0; nt < 4; ++nt) {
      const int krow = nt * 16 + fr;
      const int cb0r = (0 * 4 + fg) ^ (krow & 7);
      const int cb1r = (1 * 4 + fg) ^ (krow & 7);
      const bf16x8 kf0 = *(const bf16x8*)(Ks + krow * 64 + cb0r * 8);
      const bf16x8 kf1 = *(const bf16x8*)(Ks + krow * 64 + cb1r * 8);
#pragma unroll
      for (int ct = 0; ct < 2; ++ct) {
        st[ct][nt] = __builtin_amdgcn_mfma_f32_16x16x32_bf16(kf0, qf[ct][0], z, 0, 0, 0);
        st[ct][nt] = __builtin_amdgcn_mfma_f32_16x16x32_bf16(kf1, qf[ct][1], st[ct][nt], 0, 0, 0);
      }
    }

    // --- key padding mask (additive bias) ---
    float kbias[4][4];
#pragma unroll
    for (int nt = 0; nt < 4; ++nt) {
      const float4 km4 = *(const float4*)(msk + b * 1024 + kb * 64 + nt * 16 + fg * 4);
      kbias[nt][0] = (km4.x == 0.f) ? -3.0e38f : 0.f;
      kbias[nt][1] = (km4.y == 0.f) ? -3.0e38f : 0.f;
      kbias[nt][2] = (km4.z == 0.f) ? -3.0e38f : 0.f;
      kbias[nt][3] = (km4.w == 0.f) ? -3.0e38f : 0.f;
    }
#pragma unroll
    for (int ct = 0; ct < 2; ++ct)
#pragma unroll
      for (int nt = 0; nt < 4; ++nt)
#pragma unroll
        for (int g = 0; g < 4; ++g) st[ct][nt][g] += kbias[nt][g];

    // --- causal mask (diagonal tiles only) ---
    const bool edge = (kb * 64 + 63 > qw);
    if (edge) {
#pragma unroll
      for (int ct = 0; ct < 2; ++ct) {
        const int q = qw + ct * 16 + fr;
#pragma unroll
        for (int nt = 0; nt < 4; ++nt)
#pragma unroll
          for (int g = 0; g < 4; ++g) {
            const int j = kb * 64 + nt * 16 + fg * 4 + g;
            if (j > q) st[ct][nt][g] = -3.0e38f;
          }
      }
    }

    // --- online softmax: in-lane over 16 + 2 shfl_xor (cross-fg) ---
    float sc[2];
#pragma unroll
    for (int ct = 0; ct < 2; ++ct) {
      float mx = st[ct][0][0];
#pragma unroll
      for (int nt = 0; nt < 4; ++nt)
#pragma unroll
        for (int g = 0; g < 4; ++g) mx = fmaxf(mx, st[ct][nt][g]);
      mx = fmaxf(mx, __shfl_xor(mx, 16));
      mx = fmaxf(mx, __shfl_xor(mx, 32));
      const float nm = fmaxf(mrun[ct], mx);
      sc[ct] = exp2f(mrun[ct] - nm);
      mrun[ct] = nm;
      float rs = 0.f;
#pragma unroll
      for (int nt = 0; nt < 4; ++nt)
#pragma unroll
        for (int g = 0; g < 4; ++g) {
          const float p = exp2f(st[ct][nt][g] - nm);
          st[ct][nt][g] = p;
          rs += p;
        }
      rs += __shfl_xor(rs, 16);
      rs += __shfl_xor(rs, 32);
      lrun[ct] = lrun[ct] * sc[ct] + rs;
      // packed P write: row q = ct*16+fr, cols nt*16+fg*4..+3 (8B store)
#pragma unroll
      for (int nt = 0; nt < 4; ++nt) {
        bf16x4 pk;
        pk[0] = (bf16)st[ct][nt][0];
        pk[1] = (bf16)st[ct][nt][1];
        pk[2] = (bf16)st[ct][nt][2];
        pk[3] = (bf16)st[ct][nt][3];
        *(bf16x4*)(&Ps[wave][(ct * 16 + fr) * 72 + nt * 16 + fg * 4]) = pk;
      }
    }

    // --- rescale O (O rows live at q = mt*16 + fg*4 + g, sc lives at fr=q) ---
#pragma unroll
    for (int mt = 0; mt < 2; ++mt)
#pragma unroll
      for (int g = 0; g < 4; ++g) {
        const float scr = __shfl(sc[mt], fg * 4 + g);
#pragma unroll
        for (int dt = 0; dt < 4; ++dt) o[mt][dt][g] *= scr;
      }

    // --- PV: O[q][d] += P[q][k] * V[k][d] ---
#pragma unroll
    for (int jc = 0; jc < 2; ++jc) {
      bf16x8 pa[2];
#pragma unroll
      for (int mt = 0; mt < 2; ++mt)
        pa[mt] = *(const bf16x8*)(&Ps[wave][(mt * 16 + fr) * 72 + jc * 32 + fg * 8]);
#pragma unroll
      for (int dt = 0; dt < 4; ++dt) {
        const int vrow = dt * 16 + fr;
        const int cb = (jc * 4 + fg) ^ (vrow & 7);
        const bf16x8 vf = *(const bf16x8*)(Vs + vrow * 64 + cb * 8);
#pragma unroll
        for (int mt = 0; mt < 2; ++mt)
          o[mt][dt] = __builtin_amdgcn_mfma_f32_16x16x32_bf16(pa[mt], vf, o[mt][dt], 0, 0, 0);
      }
    }
  }

  // --- epilogue: O / l -> Ob[b][t][h*64+d] (bf16) ---
  float inv[2];
  inv[0] = 1.0f / lrun[0];
  inv[1] = 1.0f / lrun[1];
#pragma unroll
  for (int mt = 0; mt < 2; ++mt)
#pragma unroll
    for (int g = 0; g < 4; ++g) {
      const float invr = __shfl(inv[mt], fg * 4 + g);
      const int q = qw + mt * 16 + fg * 4 + g;
#pragma unroll
      for (int dt = 0; dt < 4; ++dt)
        Ob[((size_t)b * 1024 + q) * 1024 + h * 64 + dt * 16 + fr] =
            f2b(o[mt][dt][g] * invr);
    }
}

// ---------------- launcher ----------------
extern "C" void kernel_launch(void* const* d_in, const int* in_sizes, int n_in,
                              void* d_out, int out_size, void* d_ws, size_t ws_size,
                              hipStream_t stream) {
  (void)in_sizes; (void)n_in; (void)out_size; (void)ws_size;
  const float* x = (const float*)d_in[0];
  const float* m = (const float*)d_in[1];
  const float* w_qkv = (const float*)d_in[2];
  const float* w_out = (const float*)d_in[3];
  const float* b_out = (const float*)d_in[4];
  float* out = (float*)d_out;

  char* ws = (char*)d_ws;
  const size_t MB = 1u << 20;
  u16* Xb    = (u16*)(ws + 0);         // 16MB, reused as Ob after GEMM1
  u16* Wqkvb = (u16*)(ws + 16 * MB);   // 6MB
  u16* Woutb = (u16*)(ws + 22 * MB);   // 2MB
  u16* Qb    = (u16*)(ws + 24 * MB);   // 16MB
  u16* Kb    = (u16*)(ws + 40 * MB);   // 16MB
  u16* Vtb   = (u16*)(ws + 56 * MB);   // 16MB  -> total 72MB
  u16* Ob    = Xb;                      // alias: X dead after GEMM1

  // casts
  castk<<<4096, 256, 0, stream>>>(x, Xb, 8 * 1024 * 1024);
  castk<<<1536, 256, 0, stream>>>(w_qkv, Wqkvb, 3072 * 1024);
  castk<<<512, 256, 0, stream>>>(w_out, Woutb, 1024 * 1024);

  // GEMM1: qkv = X @ Wqkv^T, scatter to Q(scaled)/K/V^T
  gemm_bt<0><<<64 * 24, 256, 0, stream>>>(Xb, Wqkvb, 1024, 3072, 64,
                                          Qb, Kb, Vtb, nullptr, nullptr, nullptr);

  // flash attention
  attnk<<<1024, 256, 0, stream>>>(Qb, Kb, Vtb, m, Ob);

  // GEMM2: out = (O @ Wout^T + b_out) * m
  gemm_bt<1><<<64 * 8, 256, 0, stream>>>(Ob, Woutb, 1024, 1024, 64,
                                         nullptr, nullptr, nullptr, out, b_out, m);
}

// Round 3
// 174.330 us; speedup vs baseline: 1.7188x; 1.0903x over previous
//
#include <hip/hip_runtime.h>
#include <cstdint>
#include <cstddef>

typedef unsigned short u16;
typedef __bf16 bf16;
typedef bf16 __attribute__((ext_vector_type(4))) bf16x4;
typedef bf16 __attribute__((ext_vector_type(8))) bf16x8;
typedef float __attribute__((ext_vector_type(4))) f32x4;
typedef u16 __attribute__((ext_vector_type(8))) u16x8;

// SCALE * log2(e) folded into Q so softmax runs in exp2 domain
#define QSCALE 0.18033688011112042f

__device__ __forceinline__ u16 f2b(float x) {
  unsigned u = __float_as_uint(x);
  unsigned r = (u + 0x7fffu + ((u >> 16) & 1u)) >> 16;   // RNE
  return (u16)r;
}

__device__ __forceinline__ void gl_lds16(const void* g, void* lds) {
  __builtin_amdgcn_global_load_lds(
      (const __attribute__((address_space(1))) unsigned int*)g,
      (__attribute__((address_space(3))) unsigned int*)lds, 16, 0, 0);
}

// read a 16B fragment from a [rows][64] bf16 LDS tile with (row&7) chunk-XOR swizzle
__device__ __forceinline__ bf16x8 frag(const u16* half_base, int row, int kchunk) {
  const int c = kchunk ^ (row & 7);
  return *(const bf16x8*)(half_base + row * 64 + c * 8);
}

// stage a 128x64 bf16 half-tile (row-major, row stride K) into LDS, 512 threads,
// 2 x gl_lds16 per thread; global source pre-swizzled so LDS dest stays linear
__device__ __forceinline__ void stage_half(const u16* gbase, int K, char* lbase,
                                           int wave, int lane) {
  const int q0 = wave * 64 + lane;
  const int r0 = q0 >> 3, c0 = (q0 & 7) ^ (r0 & 7);
  gl_lds16(gbase + (size_t)r0 * K + c0 * 8, lbase + wave * 1024);
  const int q1 = q0 + 512;
  const int r1 = q1 >> 3, c1 = (q1 & 7) ^ (r1 & 7);
  gl_lds16(gbase + (size_t)r1 * K + c1 * 8, lbase + 8192 + wave * 1024);
}

// same for 256-thread blocks: 128x64 tile, 4 x gl_lds16 per thread
__device__ __forceinline__ void stage_tile4(const u16* gbase, int K, char* lbase,
                                            int wave, int lane) {
#pragma unroll
  for (int i = 0; i < 4; ++i) {
    const int q = wave * 64 + lane + i * 256;
    const int r = q >> 3, c = (q & 7) ^ (r & 7);
    gl_lds16(gbase + (size_t)r * K + c * 8, lbase + i * 4096 + wave * 1024);
  }
}

// ---------------- cast fp32 -> bf16 (vectorized) ----------------
__global__ __launch_bounds__(256) void castk(const float* __restrict__ in,
                                             u16* __restrict__ out, int n) {
  int i = (blockIdx.x * 256 + threadIdx.x) * 8;
  if (i >= n) return;
  float4 a = *(const float4*)(in + i);
  float4 b = *(const float4*)(in + i + 4);
  u16x8 v;
  v[0] = f2b(a.x); v[1] = f2b(a.y); v[2] = f2b(a.z); v[3] = f2b(a.w);
  v[4] = f2b(b.x); v[5] = f2b(b.y); v[6] = f2b(b.z); v[7] = f2b(b.w);
  *(u16x8*)(out + i) = v;
}

// ---------------- GEMM1: 256x256 8-phase, C = A(8192x1024) * B(3072x1024)^T ---
// scatter epilogue -> Q(scaled)/K/V^T.  8 waves (2M x 4N), BK=64, 128KB LDS.
__global__ __launch_bounds__(512, 2) void gemm256(
    const u16* __restrict__ A, const u16* __restrict__ B,
    u16* __restrict__ Qo, u16* __restrict__ Ko, u16* __restrict__ Vo) {
  __shared__ u16 As[2][2][128 * 64];   // [buf][Mhalf][row*64+col]
  __shared__ u16 Bs[2][2][128 * 64];   // [buf][Nhalf][row*64+col]
  const int tid = threadIdx.x;
  const int lane = tid & 63, wave = tid >> 6;
  const int fr = lane & 15, fg = lane >> 4;
  const int wm = wave >> 2, wn = wave & 3;
  const int bid = blockIdx.x;
  const int bm = bid & 31, bn = bid >> 5;
  const int K = 1024;
  const u16* Ab = A + (size_t)bm * 256 * K;
  const u16* Bb = B + (size_t)bn * 256 * K;

  f32x4 acc[8][4] = {};

  // prologue: tile0 (A both halves, B both halves) + B of tile1
  stage_half(Ab, K, (char*)&As[0][0][0], wave, lane);
  stage_half(Ab + 128 * K, K, (char*)&As[0][1][0], wave, lane);
  stage_half(Bb, K, (char*)&Bs[0][0][0], wave, lane);
  stage_half(Bb + 128 * K, K, (char*)&Bs[0][1][0], wave, lane);
  stage_half(Bb + 64, K, (char*)&Bs[1][0][0], wave, lane);
  stage_half(Bb + 128 * K + 64, K, (char*)&Bs[1][1][0], wave, lane);
  asm volatile("s_waitcnt vmcnt(4)" ::: "memory");   // tile0 landed; B(1) may fly
  __builtin_amdgcn_s_barrier();

#pragma unroll 1
  for (int j = 0; j < 8; ++j) {                      // computes tiles 2j, 2j+1
    const bool lastj = (j == 7);
#pragma unroll
    for (int half = 0; half < 2; ++half) {
      const u16* Ah = &As[half][wm][0];
      const u16* Bh = &Bs[half][wn >> 1][0];
      const int brow = (wn & 1) * 64;
      bf16x8 bfr[4][2];
#pragma unroll
      for (int q = 0; q < 4; ++q) {
        // --- ds reads: A quarter (4), + B half at q==0 (8) ---
        bf16x8 afr[2][2];
#pragma unroll
        for (int f = 0; f < 2; ++f)
#pragma unroll
          for (int kk = 0; kk < 2; ++kk)
            afr[f][kk] = frag(Ah, q * 32 + f * 16 + fr, kk * 4 + fg);
        if (q == 0) {
#pragma unroll
          for (int nf = 0; nf < 4; ++nf)
#pragma unroll
            for (int kk = 0; kk < 2; ++kk)
              bfr[nf][kk] = frag(Bh, brow + nf * 16 + fr, kk * 4 + fg);
        }
        // --- stage schedule (counted vmcnt only at phases 4/8) ---
        if (half == 0) {
          if (q == 0) {            // A(2j+1) -> buf1 (its old data read last iter)
            stage_half(Ab + (size_t)(2 * j + 1) * 64, K, (char*)&As[1][0][0], wave, lane);
            stage_half(Ab + 128 * K + (size_t)(2 * j + 1) * 64, K, (char*)&As[1][1][0], wave, lane);
          } else if (q == 1 && !lastj) {   // B0(2j+2) (B(2j) fully read at ph1)
            stage_half(Bb + (size_t)(2 * j + 2) * 64, K, (char*)&Bs[0][0][0], wave, lane);
          } else if (q == 2 && !lastj) {
            stage_half(Bb + 128 * K + (size_t)(2 * j + 2) * 64, K, (char*)&Bs[0][1][0], wave, lane);
          } else if (q == 3) {
            if (lastj) asm volatile("s_waitcnt vmcnt(0)" ::: "memory");
            else       asm volatile("s_waitcnt vmcnt(4)" ::: "memory");
          }
        } else if (!lastj) {
          if (q == 0) {            // A(2j+2) -> buf0 (read finished at ph4)
            stage_half(Ab + (size_t)(2 * j + 2) * 64, K, (char*)&As[0][0][0], wave, lane);
            stage_half(Ab + 128 * K + (size_t)(2 * j + 2) * 64, K, (char*)&As[0][1][0], wave, lane);
          } else if (q == 1) {     // B0(2j+3) (B(2j+1) fully read at ph5)
            stage_half(Bb + (size_t)(2 * j + 3) * 64, K, (char*)&Bs[1][0][0], wave, lane);
          } else if (q == 2) {
            stage_half(Bb + 128 * K + (size_t)(2 * j + 3) * 64, K, (char*)&Bs[1][1][0], wave, lane);
          } else if (q == 3) {
            asm volatile("s_waitcnt vmcnt(4)" ::: "memory");
          }
        }
        __builtin_amdgcn_s_barrier();
        asm volatile("s_waitcnt lgkmcnt(0)" ::: "memory");
        __builtin_amdgcn_sched_barrier(0);
        __builtin_amdgcn_s_setprio(1);
#pragma unroll
        for (int f = 0; f < 2; ++f)
#pragma unroll
          for (int nf = 0; nf < 4; ++nf)
#pragma unroll
            for (int kk = 0; kk < 2; ++kk)
              acc[q * 2 + f][nf] = __builtin_amdgcn_mfma_f32_16x16x32_bf16(
                  afr[f][kk], bfr[nf][kk], acc[q * 2 + f][nf], 0, 0, 0);
        __builtin_amdgcn_s_setprio(0);
        __builtin_amdgcn_s_barrier();
      }
    }
  }

  // --- scatter epilogue: Q(scaled) / K / V^T ---
  const int gr0 = bm * 256 + wm * 128;
  const int gc0 = bn * 256 + wn * 64;
  const int region = gc0 >> 10;   // block-uniform (bn*256 aligned to region grid)
#pragma unroll
  for (int mf = 0; mf < 8; ++mf) {
    const int rb = gr0 + mf * 16 + fg * 4;
    const int b = rb >> 10, t = rb & 1023;
#pragma unroll
    for (int nf = 0; nf < 4; ++nf) {
      const int c = gc0 + nf * 16 + fr;
      const int cc = c & 1023;
      const int h = cc >> 6, d = cc & 63;
      const size_t bh = (size_t)(b * 16 + h);
      if (region == 0) {
#pragma unroll
        for (int g = 0; g < 4; ++g)
          Qo[(bh * 1024 + t + g) * 64 + d] = f2b(acc[mf][nf][g] * QSCALE);
      } else if (region == 1) {
#pragma unroll
        for (int g = 0; g < 4; ++g)
          Ko[(bh * 1024 + t + g) * 64 + d] = f2b(acc[mf][nf][g]);
      } else {
        ushort4 pv;
        pv.x = f2b(acc[mf][nf][0]);
        pv.y = f2b(acc[mf][nf][1]);
        pv.z = f2b(acc[mf][nf][2]);
        pv.w = f2b(acc[mf][nf][3]);
        *(ushort4*)(Vo + (bh * 64 + d) * 1024 + t) = pv;   // V^T: [bh][d][t]
      }
    }
  }
}

// ---------------- GEMM2: 128x128, BK=64, 2-phase prefetch, swizzled LDS -------
// out = (O @ Wout^T + bias) * msk ; fp32 out
__global__ __launch_bounds__(256) void gemm_bt2(
    const u16* __restrict__ A, const u16* __restrict__ B,
    float* __restrict__ Co, const float* __restrict__ bias,
    const float* __restrict__ msk) {
  __shared__ u16 As[2][128 * 64];
  __shared__ u16 Bs[2][128 * 64];
  const int tid = threadIdx.x;
  const int lane = tid & 63, wave = tid >> 6;
  const int fr = lane & 15, fg = lane >> 4;
  const int wr = wave >> 1, wc = wave & 1;
  const int bid = blockIdx.x;
  const int bm = bid & 63, bn = bid >> 6;
  const int K = 1024, N = 1024;
  const u16* Ab = A + (size_t)bm * 128 * K;
  const u16* Bb = B + (size_t)bn * 128 * K;

  f32x4 acc[4][4] = {};

  stage_tile4(Ab, K, (char*)&As[0][0], wave, lane);
  stage_tile4(Bb, K, (char*)&Bs[0][0], wave, lane);
  __syncthreads();

  int cur = 0;
#pragma unroll 1
  for (int t = 0; t < 16; ++t) {
    if (t < 15) {   // prefetch next K-tile while computing this one
      stage_tile4(Ab + (size_t)(t + 1) * 64, K, (char*)&As[cur ^ 1][0], wave, lane);
      stage_tile4(Bb + (size_t)(t + 1) * 64, K, (char*)&Bs[cur ^ 1][0], wave, lane);
    }
    bf16x8 af[4][2], bfv[4][2];
#pragma unroll
    for (int mi = 0; mi < 4; ++mi)
#pragma unroll
      for (int kk = 0; kk < 2; ++kk)
        af[mi][kk] = frag(&As[cur][0], wr * 64 + mi * 16 + fr, kk * 4 + fg);
#pragma unroll
    for (int ni = 0; ni < 4; ++ni)
#pragma unroll
      for (int kk = 0; kk < 2; ++kk)
        bfv[ni][kk] = frag(&Bs[cur][0], wc * 64 + ni * 16 + fr, kk * 4 + fg);
#pragma unroll
    for (int mi = 0; mi < 4; ++mi)
#pragma unroll
      for (int ni = 0; ni < 4; ++ni)
#pragma unroll
        for (int kk = 0; kk < 2; ++kk)
          acc[mi][ni] = __builtin_amdgcn_mfma_f32_16x16x32_bf16(
              af[mi][kk], bfv[ni][kk], acc[mi][ni], 0, 0, 0);
    __syncthreads();   // drains prefetch vmem + lgkm; all waves done with buf
    cur ^= 1;
  }

  const int gr0 = bm * 128 + wr * 64;
  const int gc0 = bn * 128 + wc * 64;
#pragma unroll
  for (int mi = 0; mi < 4; ++mi) {
    const int rb = gr0 + mi * 16 + fg * 4;
#pragma unroll
    for (int ni = 0; ni < 4; ++ni) {
      const int c = gc0 + ni * 16 + fr;
      const float bo = bias[c];
#pragma unroll
      for (int g = 0; g < 4; ++g) {
        const int r = rb + g;
        Co[(size_t)r * N + c] = (acc[mi][ni][g] + bo) * msk[r];
      }
    }
  }
}

// ---------------- causal flash attention, bf16 MFMA, swapped-QK^T softmax ---
__global__ __launch_bounds__(256) void attnk(const u16* __restrict__ Qb,
                                             const u16* __restrict__ Kb,
                                             const u16* __restrict__ Vtb,
                                             const float* __restrict__ msk,
                                             u16* __restrict__ Ob) {
  __shared__ u16 Ks[64 * 64];        // [t][d], XOR-swizzled via staged source
  __shared__ u16 Vs[64 * 64];        // [d][t], XOR-swizzled via staged source
  __shared__ u16 Ps[4][32 * 72];     // per-wave P tile [q][k], stride 72
  const int tid = threadIdx.x;
  const int lane = tid & 63, wave = tid >> 6;
  const int fr = lane & 15, fg = lane >> 4;
  const int bid = blockIdx.x;
  __constant__ static const int tab[8] = {7, 6, 0, 1, 5, 4, 2, 3};
  const int qi = tab[bid >> 7];
  const int bh = bid & 127;
  const int b = bh >> 4, h = bh & 15;
  const int qw = qi * 128 + wave * 32;

  bf16x8 qf[2][2];
#pragma unroll
  for (int ct = 0; ct < 2; ++ct)
#pragma unroll
    for (int kc = 0; kc < 2; ++kc)
      qf[ct][kc] = *(const bf16x8*)(Qb + ((size_t)bh * 1024 + qw + ct * 16 + fr) * 64 +
                                    kc * 32 + fg * 8);

  f32x4 o[2][4] = {};
  float mrun[2], lrun[2];
  mrun[0] = mrun[1] = -3.0e38f;
  lrun[0] = lrun[1] = 0.f;

  const int cc0 = wave * 64 + lane;
  const int krow0 = cc0 >> 3, kcb0 = (cc0 & 7) ^ (krow0 & 7);
  const int cc1 = 256 + cc0;
  const int krow1 = cc1 >> 3, kcb1 = (cc1 & 7) ^ (krow1 & 7);

  const int nkb = qi * 2 + 2;
  for (int kb = 0; kb < nkb; ++kb) {
    __syncthreads();
    gl_lds16(Kb + ((size_t)bh * 1024 + kb * 64 + krow0) * 64 + kcb0 * 8,
             (char*)Ks + wave * 1024);
    gl_lds16(Vtb + ((size_t)bh * 64 + krow0) * 1024 + kb * 64 + kcb0 * 8,
             (char*)Vs + wave * 1024);
    gl_lds16(Kb + ((size_t)bh * 1024 + kb * 64 + krow1) * 64 + kcb1 * 8,
             (char*)Ks + 4096 + wave * 1024);
    gl_lds16(Vtb + ((size_t)bh * 64 + krow1) * 1024 + kb * 64 + kcb1 * 8,
             (char*)Vs + 4096 + wave * 1024);
    __syncthreads();
    if (kb * 64 > qw + 31) continue;  // fully masked for this wave (barrier counts match)

    // --- S^T = K * Q^T : lane owns q-col = ct*16+fr, rows k = nt*16+fg*4+g ---
    f32x4 st[2][4];                  // [ct][nt]
    const f32x4 z = {0.f, 0.f, 0.f, 0.f};
#pragma unroll
    for (int nt = 0; nt < 4; ++nt) {
      const int krow = nt * 16 + fr;
      const int cb0r = (0 * 4 + fg) ^ (krow & 7);
      const int cb1r = (1 * 4 + fg) ^ (krow & 7);
      const bf16x8 kf0 = *(const bf16x8*)(Ks + krow * 64 + cb0r * 8);
      const bf16x8 kf1 = *(const bf16x8*)(Ks + krow * 64 + cb1r * 8);
#pragma unroll
      for (int ct = 0; ct < 2; ++ct) {
        st[ct][nt] = __builtin_amdgcn_mfma_f32_16x16x32_bf16(kf0, qf[ct][0], z, 0, 0, 0);
        st[ct][nt] = __builtin_amdgcn_mfma_f32_16x16x32_bf16(kf1, qf[ct][1], st[ct][nt], 0, 0, 0);
      }
    }

    // --- key padding mask (additive bias) ---
    float kbias[4][4];
#pragma unroll
    for (int nt = 0; nt < 4; ++nt) {
      const float4 km4 = *(const float4*)(msk + b * 1024 + kb * 64 + nt * 16 + fg * 4);
      kbias[nt][0] = (km4.x == 0.f) ? -3.0e38f : 0.f;
      kbias[nt][1] = (km4.y == 0.f) ? -3.0e38f : 0.f;
      kbias[nt][2] = (km4.z == 0.f) ? -3.0e38f : 0.f;
      kbias[nt][3] = (km4.w == 0.f) ? -3.0e38f : 0.f;
    }
#pragma unroll
    for (int ct = 0; ct < 2; ++ct)
#pragma unroll
      for (int nt = 0; nt < 4; ++nt)
#pragma unroll
        for (int g = 0; g < 4; ++g) st[ct][nt][g] += kbias[nt][g];

    // --- causal mask (diagonal tiles only) ---
    const bool edge = (kb * 64 + 63 > qw);
    if (edge) {
#pragma unroll
      for (int ct = 0; ct < 2; ++ct) {
        const int q = qw + ct * 16 + fr;
#pragma unroll
        for (int nt = 0; nt < 4; ++nt)
#pragma unroll
          for (int g = 0; g < 4; ++g) {
            const int j = kb * 64 + nt * 16 + fg * 4 + g;
            if (j > q) st[ct][nt][g] = -3.0e38f;
          }
      }
    }

    // --- online softmax: in-lane over 16 + 2 shfl_xor (cross-fg) ---
    float sc[2];
#pragma unroll
    for (int ct = 0; ct < 2; ++ct) {
      float mx = st[ct][0][0];
#pragma unroll
      for (int nt = 0; nt < 4; ++nt)
#pragma unroll
        for (int g = 0; g < 4; ++g) mx = fmaxf(mx, st[ct][nt][g]);
      mx = fmaxf(mx, __shfl_xor(mx, 16));
      mx = fmaxf(mx, __shfl_xor(mx, 32));
      const float nm = fmaxf(mrun[ct], mx);
      sc[ct] = exp2f(mrun[ct] - nm);
      mrun[ct] = nm;
      float rs = 0.f;
#pragma unroll
      for (int nt = 0; nt < 4; ++nt)
#pragma unroll
        for (int g = 0; g < 4; ++g) {
          const float p = exp2f(st[ct][nt][g] - nm);
          st[ct][nt][g] = p;
          rs += p;
        }
      rs += __shfl_xor(rs, 16);
      rs += __shfl_xor(rs, 32);
      lrun[ct] = lrun[ct] * sc[ct] + rs;
      // packed P write: row q = ct*16+fr, cols nt*16+fg*4..+3 (8B store)
#pragma unroll
      for (int nt = 0; nt < 4; ++nt) {
        bf16x4 pk;
        pk[0] = (bf16)st[ct][nt][0];
        pk[1] = (bf16)st[ct][nt][1];
        pk[2] = (bf16)st[ct][nt][2];
        pk[3] = (bf16)st[ct][nt][3];
        *(bf16x4*)(&Ps[wave][(ct * 16 + fr) * 72 + nt * 16 + fg * 4]) = pk;
      }
    }

    // --- rescale O (O rows live at q = mt*16 + fg*4 + g, sc lives at fr=q) ---
#pragma unroll
    for (int mt = 0; mt < 2; ++mt)
#pragma unroll
      for (int g = 0; g < 4; ++g) {
        const float scr = __shfl(sc[mt], fg * 4 + g);
#pragma unroll
        for (int dt = 0; dt < 4; ++dt) o[mt][dt][g] *= scr;
      }

    // --- PV: O[q][d] += P[q][k] * V[k][d] ---
#pragma unroll
    for (int jc = 0; jc < 2; ++jc) {
      bf16x8 pa[2];
#pragma unroll
      for (int mt = 0; mt < 2; ++mt)
        pa[mt] = *(const bf16x8*)(&Ps[wave][(mt * 16 + fr) * 72 + jc * 32 + fg * 8]);
#pragma unroll
      for (int dt = 0; dt < 4; ++dt) {
        const int vrow = dt * 16 + fr;
        const int cb = (jc * 4 + fg) ^ (vrow & 7);
        const bf16x8 vf = *(const bf16x8*)(Vs + vrow * 64 + cb * 8);
#pragma unroll
        for (int mt = 0; mt < 2; ++mt)
          o[mt][dt] = __builtin_amdgcn_mfma_f32_16x16x32_bf16(pa[mt], vf, o[mt][dt], 0, 0, 0);
      }
    }
  }

  // --- epilogue: O / l -> Ob[b][t][h*64+d] (bf16) ---
  float inv[2];
  inv[0] = 1.0f / lrun[0];
  inv[1] = 1.0f / lrun[1];
#pragma unroll
  for (int mt = 0; mt < 2; ++mt)
#pragma unroll
    for (int g = 0; g < 4; ++g) {
      const float invr = __shfl(inv[mt], fg * 4 + g);
      const int q = qw + mt * 16 + fg * 4 + g;
#pragma unroll
      for (int dt = 0; dt < 4; ++dt)
        Ob[((size_t)b * 1024 + q) * 1024 + h * 64 + dt * 16 + fr] =
            f2b(o[mt][dt][g] * invr);
    }
}

// ---------------- launcher ----------------
extern "C" void kernel_launch(void* const* d_in, const int* in_sizes, int n_in,
                              void* d_out, int out_size, void* d_ws, size_t ws_size,
                              hipStream_t stream) {
  (void)in_sizes; (void)n_in; (void)out_size; (void)ws_size;
  const float* x = (const float*)d_in[0];
  const float* m = (const float*)d_in[1];
  const float* w_qkv = (const float*)d_in[2];
  const float* w_out = (const float*)d_in[3];
  const float* b_out = (const float*)d_in[4];
  float* out = (float*)d_out;

  char* ws = (char*)d_ws;
  const size_t MB = 1u << 20;
  u16* Xb    = (u16*)(ws + 0);         // 16MB, reused as Ob after GEMM1
  u16* Wqkvb = (u16*)(ws + 16 * MB);   // 6MB
  u16* Woutb = (u16*)(ws + 22 * MB);   // 2MB
  u16* Qb    = (u16*)(ws + 24 * MB);   // 16MB
  u16* Kb    = (u16*)(ws + 40 * MB);   // 16MB
  u16* Vtb   = (u16*)(ws + 56 * MB);   // 16MB  -> total 72MB
  u16* Ob    = Xb;                      // alias: X dead after GEMM1

  // casts
  castk<<<4096, 256, 0, stream>>>(x, Xb, 8 * 1024 * 1024);
  castk<<<1536, 256, 0, stream>>>(w_qkv, Wqkvb, 3072 * 1024);
  castk<<<512, 256, 0, stream>>>(w_out, Woutb, 1024 * 1024);

  // GEMM1: qkv = X @ Wqkv^T (256^2 8-phase), scatter to Q(scaled)/K/V^T
  gemm256<<<384, 512, 0, stream>>>(Xb, Wqkvb, Qb, Kb, Vtb);

  // flash attention
  attnk<<<1024, 256, 0, stream>>>(Qb, Kb, Vtb, m, Ob);

  // GEMM2: out = (O @ Wout^T + b_out) * m  (128^2, 2-phase)
  gemm_bt2<<<512, 256, 0, stream>>>(Ob, Woutb, out, b_out, m);
}

// Round 4
// 169.074 us; speedup vs baseline: 1.7722x; 1.0311x over previous
//
#include <hip/hip_runtime.h>
#include <cstdint>
#include <cstddef>

typedef unsigned short u16;
typedef __bf16 bf16;
typedef bf16 __attribute__((ext_vector_type(4))) bf16x4;
typedef bf16 __attribute__((ext_vector_type(8))) bf16x8;
typedef float __attribute__((ext_vector_type(4))) f32x4;
typedef u16 __attribute__((ext_vector_type(8))) u16x8;

// SCALE * log2(e) folded into Q so softmax runs in exp2 domain
#define QSCALE 0.18033688011112042f

__device__ __forceinline__ u16 f2b(float x) {
  unsigned u = __float_as_uint(x);
  unsigned r = (u + 0x7fffu + ((u >> 16) & 1u)) >> 16;   // RNE
  return (u16)r;
}

__device__ __forceinline__ void gl_lds16(const void* g, void* lds) {
  __builtin_amdgcn_global_load_lds(
      (const __attribute__((address_space(1))) unsigned int*)g,
      (__attribute__((address_space(3))) unsigned int*)lds, 16, 0, 0);
}

// read a 16B fragment from a [rows][64] bf16 LDS tile with (row&7) chunk-XOR swizzle
__device__ __forceinline__ bf16x8 frag(const u16* base, int row, int kchunk) {
  const int c = kchunk ^ (row & 7);
  return *(const bf16x8*)(base + row * 64 + c * 8);
}

// stage a 128x64 bf16 tile (row stride K) into LDS; 256 threads, 4 gl_lds each;
// global source pre-swizzled so LDS dest stays linear (rule #21)
__device__ __forceinline__ void stage_tile4(const u16* gbase, int K, char* lbase,
                                            int wave, int lane) {
#pragma unroll
  for (int i = 0; i < 4; ++i) {
    const int q = wave * 64 + lane + i * 256;
    const int r = q >> 3, c = (q & 7) ^ (r & 7);
    gl_lds16(gbase + (size_t)r * K + c * 8, lbase + i * 4096 + wave * 1024);
  }
}

// ---------------- cast fp32 -> bf16 (vectorized) ----------------
__global__ __launch_bounds__(256) void castk(const float* __restrict__ in,
                                             u16* __restrict__ out, int n) {
  int i = (blockIdx.x * 256 + threadIdx.x) * 8;
  if (i >= n) return;
  float4 a = *(const float4*)(in + i);
  float4 b = *(const float4*)(in + i + 4);
  u16x8 v;
  v[0] = f2b(a.x); v[1] = f2b(a.y); v[2] = f2b(a.z); v[3] = f2b(a.w);
  v[4] = f2b(b.x); v[5] = f2b(b.y); v[6] = f2b(b.z); v[7] = f2b(b.w);
  *(u16x8*)(out + i) = v;
}

// ---------------- GEMM1: 128x128, BK=64, dbuf, 1 sync/iter, swizzled --------
// qkv = X(8192x1024) @ Wqkv(3072x1024)^T, scatter epilogue -> Q(scaled)/K/V^T.
// 64KB LDS -> 2 blocks/CU; grid 1536 = 6/CU exactly.
__global__ __launch_bounds__(256) void gemm_qkv(
    const u16* __restrict__ A, const u16* __restrict__ B,
    u16* __restrict__ Qo, u16* __restrict__ Ko, u16* __restrict__ Vo) {
  __shared__ u16 As[2][128 * 64];
  __shared__ u16 Bs[2][128 * 64];
  const int tid = threadIdx.x;
  const int lane = tid & 63, wave = tid >> 6;
  const int fr = lane & 15, fg = lane >> 4;
  const int wr = wave >> 1, wc = wave & 1;
  const int bid = blockIdx.x;
  const int bm = bid & 63, bn = bid >> 6;
  const int K = 1024;
  const u16* Ab = A + (size_t)bm * 128 * K;
  const u16* Bb = B + (size_t)bn * 128 * K;

  f32x4 acc[4][4] = {};

  stage_tile4(Ab, K, (char*)&As[0][0], wave, lane);
  stage_tile4(Bb, K, (char*)&Bs[0][0], wave, lane);
  __syncthreads();

  int cur = 0;
#pragma unroll 1
  for (int t = 0; t < 16; ++t) {
    if (t < 15) {   // prefetch next K-tile while computing this one
      stage_tile4(Ab + (size_t)(t + 1) * 64, K, (char*)&As[cur ^ 1][0], wave, lane);
      stage_tile4(Bb + (size_t)(t + 1) * 64, K, (char*)&Bs[cur ^ 1][0], wave, lane);
    }
    bf16x8 af[4][2], bfv[4][2];
#pragma unroll
    for (int mi = 0; mi < 4; ++mi)
#pragma unroll
      for (int kk = 0; kk < 2; ++kk)
        af[mi][kk] = frag(&As[cur][0], wr * 64 + mi * 16 + fr, kk * 4 + fg);
#pragma unroll
    for (int ni = 0; ni < 4; ++ni)
#pragma unroll
      for (int kk = 0; kk < 2; ++kk)
        bfv[ni][kk] = frag(&Bs[cur][0], wc * 64 + ni * 16 + fr, kk * 4 + fg);
#pragma unroll
    for (int mi = 0; mi < 4; ++mi)
#pragma unroll
      for (int ni = 0; ni < 4; ++ni)
#pragma unroll
        for (int kk = 0; kk < 2; ++kk)
          acc[mi][ni] = __builtin_amdgcn_mfma_f32_16x16x32_bf16(
              af[mi][kk], bfv[ni][kk], acc[mi][ni], 0, 0, 0);
    __syncthreads();   // drains prefetch vmem + lgkm; all waves done with buf
    cur ^= 1;
  }

  // --- scatter epilogue: Q(scaled) / K / V^T ---
  const int gr0 = bm * 128 + wr * 64;
  const int gc0 = bn * 128 + wc * 64;
#pragma unroll
  for (int mi = 0; mi < 4; ++mi) {
    const int rb = gr0 + mi * 16 + fg * 4;
    const int b = rb >> 10, t = rb & 1023;
#pragma unroll
    for (int ni = 0; ni < 4; ++ni) {
      const int c = gc0 + ni * 16 + fr;
      const int region = c >> 10, cc = c & 1023;
      const int h = cc >> 6, d = cc & 63;
      const size_t bh = (size_t)(b * 16 + h);
      if (region == 0) {
#pragma unroll
        for (int g = 0; g < 4; ++g)
          Qo[(bh * 1024 + t + g) * 64 + d] = f2b(acc[mi][ni][g] * QSCALE);
      } else if (region == 1) {
#pragma unroll
        for (int g = 0; g < 4; ++g)
          Ko[(bh * 1024 + t + g) * 64 + d] = f2b(acc[mi][ni][g]);
      } else {
        ushort4 pv;
        pv.x = f2b(acc[mi][ni][0]);
        pv.y = f2b(acc[mi][ni][1]);
        pv.z = f2b(acc[mi][ni][2]);
        pv.w = f2b(acc[mi][ni][3]);
        *(ushort4*)(Vo + (bh * 64 + d) * 1024 + t) = pv;   // V^T: [bh][d][t]
      }
    }
  }
}

// ---------------- GEMM2: 128x128, BK=64, dbuf, 1 sync/iter, swizzled --------
// out = (O @ Wout^T + bias) * msk ; fp32 out
__global__ __launch_bounds__(256) void gemm_bt2(
    const u16* __restrict__ A, const u16* __restrict__ B,
    float* __restrict__ Co, const float* __restrict__ bias,
    const float* __restrict__ msk) {
  __shared__ u16 As[2][128 * 64];
  __shared__ u16 Bs[2][128 * 64];
  const int tid = threadIdx.x;
  const int lane = tid & 63, wave = tid >> 6;
  const int fr = lane & 15, fg = lane >> 4;
  const int wr = wave >> 1, wc = wave & 1;
  const int bid = blockIdx.x;
  const int bm = bid & 63, bn = bid >> 6;
  const int K = 1024, N = 1024;
  const u16* Ab = A + (size_t)bm * 128 * K;
  const u16* Bb = B + (size_t)bn * 128 * K;

  f32x4 acc[4][4] = {};

  stage_tile4(Ab, K, (char*)&As[0][0], wave, lane);
  stage_tile4(Bb, K, (char*)&Bs[0][0], wave, lane);
  __syncthreads();

  int cur = 0;
#pragma unroll 1
  for (int t = 0; t < 16; ++t) {
    if (t < 15) {
      stage_tile4(Ab + (size_t)(t + 1) * 64, K, (char*)&As[cur ^ 1][0], wave, lane);
      stage_tile4(Bb + (size_t)(t + 1) * 64, K, (char*)&Bs[cur ^ 1][0], wave, lane);
    }
    bf16x8 af[4][2], bfv[4][2];
#pragma unroll
    for (int mi = 0; mi < 4; ++mi)
#pragma unroll
      for (int kk = 0; kk < 2; ++kk)
        af[mi][kk] = frag(&As[cur][0], wr * 64 + mi * 16 + fr, kk * 4 + fg);
#pragma unroll
    for (int ni = 0; ni < 4; ++ni)
#pragma unroll
      for (int kk = 0; kk < 2; ++kk)
        bfv[ni][kk] = frag(&Bs[cur][0], wc * 64 + ni * 16 + fr, kk * 4 + fg);
#pragma unroll
    for (int mi = 0; mi < 4; ++mi)
#pragma unroll
      for (int ni = 0; ni < 4; ++ni)
#pragma unroll
        for (int kk = 0; kk < 2; ++kk)
          acc[mi][ni] = __builtin_amdgcn_mfma_f32_16x16x32_bf16(
              af[mi][kk], bfv[ni][kk], acc[mi][ni], 0, 0, 0);
    __syncthreads();
    cur ^= 1;
  }

  const int gr0 = bm * 128 + wr * 64;
  const int gc0 = bn * 128 + wc * 64;
#pragma unroll
  for (int mi = 0; mi < 4; ++mi) {
    const int rb = gr0 + mi * 16 + fg * 4;
#pragma unroll
    for (int ni = 0; ni < 4; ++ni) {
      const int c = gc0 + ni * 16 + fr;
      const float bo = bias[c];
#pragma unroll
      for (int g = 0; g < 4; ++g) {
        const int r = rb + g;
        Co[(size_t)r * N + c] = (acc[mi][ni][g] + bo) * msk[r];
      }
    }
  }
}

// ---------------- causal flash attention: dbuf K/V, 1 sync/iter -------------
__global__ __launch_bounds__(256) void attnk(const u16* __restrict__ Qb,
                                             const u16* __restrict__ Kb,
                                             const u16* __restrict__ Vtb,
                                             const float* __restrict__ msk,
                                             u16* __restrict__ Ob) {
  __shared__ u16 Ks[2][64 * 64];     // [t][d], XOR-swizzled via staged source
  __shared__ u16 Vs[2][64 * 64];     // [d][t], XOR-swizzled via staged source
  __shared__ u16 Ps[4][32 * 72];     // per-wave P tile [q][k], stride 72
  const int tid = threadIdx.x;
  const int lane = tid & 63, wave = tid >> 6;
  const int fr = lane & 15, fg = lane >> 4;
  const int bid = blockIdx.x;
  __constant__ static const int tab[8] = {7, 6, 0, 1, 5, 4, 2, 3};
  const int qi = tab[bid >> 7];
  const int bh = bid & 127;
  const int b = bh >> 4, h = bh & 15;
  const int qw = qi * 128 + wave * 32;

  bf16x8 qf[2][2];
#pragma unroll
  for (int ct = 0; ct < 2; ++ct)
#pragma unroll
    for (int kc = 0; kc < 2; ++kc)
      qf[ct][kc] = *(const bf16x8*)(Qb + ((size_t)bh * 1024 + qw + ct * 16 + fr) * 64 +
                                    kc * 32 + fg * 8);

  f32x4 o[2][4] = {};
  float mrun[2], lrun[2];
  mrun[0] = mrun[1] = -3.0e38f;
  lrun[0] = lrun[1] = 0.f;

  const int cc0 = wave * 64 + lane;
  const int krow0 = cc0 >> 3, kcb0 = (cc0 & 7) ^ (krow0 & 7);
  const int cc1 = 256 + cc0;
  const int krow1 = cc1 >> 3, kcb1 = (cc1 & 7) ^ (krow1 & 7);

  const int nkb = qi * 2 + 2;

  // prologue: stage kb=0 into buf 0
  gl_lds16(Kb + ((size_t)bh * 1024 + krow0) * 64 + kcb0 * 8, (char*)&Ks[0][0] + wave * 1024);
  gl_lds16(Vtb + ((size_t)bh * 64 + krow0) * 1024 + kcb0 * 8, (char*)&Vs[0][0] + wave * 1024);
  gl_lds16(Kb + ((size_t)bh * 1024 + krow1) * 64 + kcb1 * 8, (char*)&Ks[0][0] + 4096 + wave * 1024);
  gl_lds16(Vtb + ((size_t)bh * 64 + krow1) * 1024 + kcb1 * 8, (char*)&Vs[0][0] + 4096 + wave * 1024);

#pragma unroll 1
  for (int kb = 0; kb < nkb; ++kb) {
    __syncthreads();   // stage(kb) landed (implicit vmcnt0); compute(kb-1) done
    if (kb + 1 < nkb) {   // prefetch kb+1 into other buffer; hides under compute
      char* kd = (char*)&Ks[(kb + 1) & 1][0];
      char* vd = (char*)&Vs[(kb + 1) & 1][0];
      gl_lds16(Kb + ((size_t)bh * 1024 + (kb + 1) * 64 + krow0) * 64 + kcb0 * 8, kd + wave * 1024);
      gl_lds16(Vtb + ((size_t)bh * 64 + krow0) * 1024 + (kb + 1) * 64 + kcb0 * 8, vd + wave * 1024);
      gl_lds16(Kb + ((size_t)bh * 1024 + (kb + 1) * 64 + krow1) * 64 + kcb1 * 8, kd + 4096 + wave * 1024);
      gl_lds16(Vtb + ((size_t)bh * 64 + krow1) * 1024 + (kb + 1) * 64 + kcb1 * 8, vd + 4096 + wave * 1024);
    }
    if (kb * 64 > qw + 31) continue;  // fully masked for this wave (sync count uniform)
    const u16* Kc = &Ks[kb & 1][0];
    const u16* Vc = &Vs[kb & 1][0];

    // --- S^T = K * Q^T : lane owns q-col = ct*16+fr, rows k = nt*16+fg*4+g ---
    f32x4 st[2][4];                  // [ct][nt]
    const f32x4 z = {0.f, 0.f, 0.f, 0.f};
#pragma unroll
    for (int nt = 0; nt < 4; ++nt) {
      const int krow = nt * 16 + fr;
      const int cb0r = (0 * 4 + fg) ^ (krow & 7);
      const int cb1r = (1 * 4 + fg) ^ (krow & 7);
      const bf16x8 kf0 = *(const bf16x8*)(Kc + krow * 64 + cb0r * 8);
      const bf16x8 kf1 = *(const bf16x8*)(Kc + krow * 64 + cb1r * 8);
#pragma unroll
      for (int ct = 0; ct < 2; ++ct) {
        st[ct][nt] = __builtin_amdgcn_mfma_f32_16x16x32_bf16(kf0, qf[ct][0], z, 0, 0, 0);
        st[ct][nt] = __builtin_amdgcn_mfma_f32_16x16x32_bf16(kf1, qf[ct][1], st[ct][nt], 0, 0, 0);
      }
    }

    // --- key padding mask (additive bias) ---
    float kbias[4][4];
#pragma unroll
    for (int nt = 0; nt < 4; ++nt) {
      const float4 km4 = *(const float4*)(msk + b * 1024 + kb * 64 + nt * 16 + fg * 4);
      kbias[nt][0] = (km4.x == 0.f) ? -3.0e38f : 0.f;
      kbias[nt][1] = (km4.y == 0.f) ? -3.0e38f : 0.f;
      kbias[nt][2] = (km4.z == 0.f) ? -3.0e38f : 0.f;
      kbias[nt][3] = (km4.w == 0.f) ? -3.0e38f : 0.f;
    }
#pragma unroll
    for (int ct = 0; ct < 2; ++ct)
#pragma unroll
      for (int nt = 0; nt < 4; ++nt)
#pragma unroll
        for (int g = 0; g < 4; ++g) st[ct][nt][g] += kbias[nt][g];

    // --- causal mask (diagonal tiles only) ---
    const bool edge = (kb * 64 + 63 > qw);
    if (edge) {
#pragma unroll
      for (int ct = 0; ct < 2; ++ct) {
        const int q = qw + ct * 16 + fr;
#pragma unroll
        for (int nt = 0; nt < 4; ++nt)
#pragma unroll
          for (int g = 0; g < 4; ++g) {
            const int j = kb * 64 + nt * 16 + fg * 4 + g;
            if (j > q) st[ct][nt][g] = -3.0e38f;
          }
      }
    }

    // --- online softmax: in-lane over 16 + 2 shfl_xor (cross-fg) ---
    float sc[2];
#pragma unroll
    for (int ct = 0; ct < 2; ++ct) {
      float mx = st[ct][0][0];
#pragma unroll
      for (int nt = 0; nt < 4; ++nt)
#pragma unroll
        for (int g = 0; g < 4; ++g) mx = fmaxf(mx, st[ct][nt][g]);
      mx = fmaxf(mx, __shfl_xor(mx, 16));
      mx = fmaxf(mx, __shfl_xor(mx, 32));
      const float nm = fmaxf(mrun[ct], mx);
      sc[ct] = exp2f(mrun[ct] - nm);
      mrun[ct] = nm;
      float rs = 0.f;
#pragma unroll
      for (int nt = 0; nt < 4; ++nt)
#pragma unroll
        for (int g = 0; g < 4; ++g) {
          const float p = exp2f(st[ct][nt][g] - nm);
          st[ct][nt][g] = p;
          rs += p;
        }
      rs += __shfl_xor(rs, 16);
      rs += __shfl_xor(rs, 32);
      lrun[ct] = lrun[ct] * sc[ct] + rs;
      // packed P write: row q = ct*16+fr, cols nt*16+fg*4..+3 (8B store)
#pragma unroll
      for (int nt = 0; nt < 4; ++nt) {
        bf16x4 pk;
        pk[0] = (bf16)st[ct][nt][0];
        pk[1] = (bf16)st[ct][nt][1];
        pk[2] = (bf16)st[ct][nt][2];
        pk[3] = (bf16)st[ct][nt][3];
        *(bf16x4*)(&Ps[wave][(ct * 16 + fr) * 72 + nt * 16 + fg * 4]) = pk;
      }
    }

    // --- rescale O (O rows live at q = mt*16 + fg*4 + g, sc lives at fr=q) ---
#pragma unroll
    for (int mt = 0; mt < 2; ++mt)
#pragma unroll
      for (int g = 0; g < 4; ++g) {
        const float scr = __shfl(sc[mt], fg * 4 + g);
#pragma unroll
        for (int dt = 0; dt < 4; ++dt) o[mt][dt][g] *= scr;
      }

    // --- PV: O[q][d] += P[q][k] * V[k][d] ---
#pragma unroll
    for (int jc = 0; jc < 2; ++jc) {
      bf16x8 pa[2];
#pragma unroll
      for (int mt = 0; mt < 2; ++mt)
        pa[mt] = *(const bf16x8*)(&Ps[wave][(mt * 16 + fr) * 72 + jc * 32 + fg * 8]);
#pragma unroll
      for (int dt = 0; dt < 4; ++dt) {
        const int vrow = dt * 16 + fr;
        const int cb = (jc * 4 + fg) ^ (vrow & 7);
        const bf16x8 vf = *(const bf16x8*)(Vc + vrow * 64 + cb * 8);
#pragma unroll
        for (int mt = 0; mt < 2; ++mt)
          o[mt][dt] = __builtin_amdgcn_mfma_f32_16x16x32_bf16(pa[mt], vf, o[mt][dt], 0, 0, 0);
      }
    }
  }

  // --- epilogue: O / l -> Ob[b][t][h*64+d] (bf16) ---
  float inv[2];
  inv[0] = 1.0f / lrun[0];
  inv[1] = 1.0f / lrun[1];
#pragma unroll
  for (int mt = 0; mt < 2; ++mt)
#pragma unroll
    for (int g = 0; g < 4; ++g) {
      const float invr = __shfl(inv[mt], fg * 4 + g);
      const int q = qw + mt * 16 + fg * 4 + g;
#pragma unroll
      for (int dt = 0; dt < 4; ++dt)
        Ob[((size_t)b * 1024 + q) * 1024 + h * 64 + dt * 16 + fr] =
            f2b(o[mt][dt][g] * invr);
    }
}

// ---------------- launcher ----------------
extern "C" void kernel_launch(void* const* d_in, const int* in_sizes, int n_in,
                              void* d_out, int out_size, void* d_ws, size_t ws_size,
                              hipStream_t stream) {
  (void)in_sizes; (void)n_in; (void)out_size; (void)ws_size;
  const float* x = (const float*)d_in[0];
  const float* m = (const float*)d_in[1];
  const float* w_qkv = (const float*)d_in[2];
  const float* w_out = (const float*)d_in[3];
  const float* b_out = (const float*)d_in[4];
  float* out = (float*)d_out;

  char* ws = (char*)d_ws;
  const size_t MB = 1u << 20;
  u16* Xb    = (u16*)(ws + 0);         // 16MB, reused as Ob after GEMM1
  u16* Wqkvb = (u16*)(ws + 16 * MB);   // 6MB
  u16* Woutb = (u16*)(ws + 22 * MB);   // 2MB
  u16* Qb    = (u16*)(ws + 24 * MB);   // 16MB
  u16* Kb    = (u16*)(ws + 40 * MB);   // 16MB
  u16* Vtb   = (u16*)(ws + 56 * MB);   // 16MB  -> total 72MB
  u16* Ob    = Xb;                      // alias: X dead after GEMM1

  // casts
  castk<<<4096, 256, 0, stream>>>(x, Xb, 8 * 1024 * 1024);
  castk<<<1536, 256, 0, stream>>>(w_qkv, Wqkvb, 3072 * 1024);
  castk<<<512, 256, 0, stream>>>(w_out, Woutb, 1024 * 1024);

  // GEMM1: qkv = X @ Wqkv^T (128^2 dbuf TLP), scatter to Q(scaled)/K/V^T
  gemm_qkv<<<1536, 256, 0, stream>>>(Xb, Wqkvb, Qb, Kb, Vtb);

  // flash attention (dbuf K/V, 1 sync per K-tile)
  attnk<<<1024, 256, 0, stream>>>(Qb, Kb, Vtb, m, Ob);

  // GEMM2: out = (O @ Wout^T + b_out) * m  (128^2, dbuf)
  gemm_bt2<<<512, 256, 0, stream>>>(Ob, Woutb, out, b_out, m);
}